// Round 1
// baseline (2231.132 us; speedup 1.0000x reference)
//
#include <hip/hip_runtime.h>
#include <hip/hip_bf16.h>

typedef short    bf16x8 __attribute__((ext_vector_type(8)));
typedef float    f32x16 __attribute__((ext_vector_type(16)));
typedef float    f32x4  __attribute__((ext_vector_type(4)));
typedef unsigned u32x4  __attribute__((ext_vector_type(4)));

#define RNN_H 128
#define RNN_T 2048
#define RNN_B 8192
#define RNN_C 10

template <typename D, typename S>
__device__ __forceinline__ D bitcast(const S& s) {
  static_assert(sizeof(D) == sizeof(S), "size mismatch");
  D d; __builtin_memcpy(&d, &s, sizeof(D)); return d;
}

__device__ __forceinline__ unsigned pk_bf16(float a0, float a1) {
  __hip_bfloat162 b2 = __float22bfloat162_rn(make_float2(a0, a1));
  unsigned u; __builtin_memcpy(&u, &b2, 4);
  return u;  // a0 in low 16, a1 in high 16
}

// Dekker-style split: a ~= hi + lo with hi,lo bf16; residual ~2^-17 * |a|
__device__ __forceinline__ void split2(float a0, float a1, unsigned &hp, unsigned &lp) {
  hp = pk_bf16(a0, a1);
  float h0 = __uint_as_float(hp << 16);
  float h1 = __uint_as_float(hp & 0xffff0000u);
  lp = pk_bf16(a0 - h0, a1 - h1);
}

__device__ __forceinline__ float fast_tanh(float a) {
  // tanh(a) = 1 - 2/(exp(2a)+1);  exp(2a) = 2^(a * 2*log2(e))
  float e = __builtin_amdgcn_exp2f(a * 2.885390081777927f);
  return 1.0f - 2.0f * __builtin_amdgcn_rcpf(e + 1.0f);
}

__device__ __forceinline__ f32x16 mfma_bf16(bf16x8 a, bf16x8 b, f32x16 c) {
  return __builtin_amdgcn_mfma_f32_32x32x16_bf16(a, b, c, 0, 0, 0);
}

__global__ __launch_bounds__(256, 1)
void rnn_fused(const float* __restrict__ x, const float* __restrict__ w_hx,
               const float* __restrict__ w_hh, const float* __restrict__ b_h,
               const float* __restrict__ w_ph, const float* __restrict__ b_p,
               float* __restrict__ out)
{
  // h state double-buffered in LDS, stored directly in MFMA B-fragment order:
  // [buf][hi/lo][ktile(8)][lane(64)] -> 8 bf16 (16B) per slot. 32 KiB total.
  // Slot (kt, l, j) holds h[k][n] with n = l&31,
  //   k = kt*16 + 4*(l>>5) + (j&3) + 8*(j>>2).
  __shared__ bf16x8 hbuf[2][2][8][64];

  const int tid  = threadIdx.x;
  const int lane = tid & 63;
  const int wv   = tid >> 6;   // wave id: owns output rows 32*wv .. 32*wv+31
  const int g    = lane >> 5;
  const int l31  = lane & 31;
  const int n0   = blockIdx.x * 32;

  // zero initial h buffer (buf 0, hi+lo halves)
  {
    bf16x8 z = {0,0,0,0,0,0,0,0};
    bf16x8* p = &hbuf[0][0][0][0];
    for (int i = tid; i < 2*8*64; i += 256) p[i] = z;
  }

  // ---- W_hh A-fragments (hi/lo bf16 split), register-resident for all T ----
  bf16x8 Ahi[8], Alo[8];
  {
    const float* wrow = w_hh + (size_t)(wv*32 + l31)*RNN_H + 4*g;
    #pragma unroll
    for (int kt = 0; kt < 8; ++kt) {
      f32x4 w0 = *(const f32x4*)(wrow + kt*16);      // k offsets 0..3
      f32x4 w1 = *(const f32x4*)(wrow + kt*16 + 8);  // k offsets 8..11
      unsigned h0,h1,h2,h3,l0,l1,l2,l3;
      split2(w0[0], w0[1], h0, l0);
      split2(w0[2], w0[3], h1, l1);
      split2(w1[0], w1[1], h2, l2);
      split2(w1[2], w1[3], h3, l3);
      u32x4 th = {h0,h1,h2,h3}, tl = {l0,l1,l2,l3};
      Ahi[kt] = bitcast<bf16x8>(th);
      Alo[kt] = bitcast<bf16x8>(tl);
    }
  }

  // per-acc-register bias and w_hx (C/D row map: m = 32*wv + (r&3)+8*(r>>2)+4*g)
  f32x16 bh6, wx6;
  #pragma unroll
  for (int r = 0; r < 16; ++r) {
    const int m = wv*32 + (r&3) + 8*(r>>2) + 4*g;
    bh6[r] = b_h[m];
    wx6[r] = w_hx[m];
  }

  // x: this lane's batch row, prefetched 4 steps at a time
  const float* px = x + (size_t)(n0 + l31) * RNN_T;
  f32x4 xc = *(const f32x4*)px;

  __syncthreads();

  for (int t4 = 0; t4 < RNN_T/4; ++t4) {
    f32x4 xn = xc;
    if (t4 + 1 < RNN_T/4) xn = *(const f32x4*)(px + 4*t4 + 4);
    #pragma unroll
    for (int q = 0; q < 4; ++q) {
      const int rb = q & 1;      // read buffer (t even -> 0)
      const int wb = rb ^ 1;     // write buffer
      const float xv = xc[q];

      f32x16 acc;
      #pragma unroll
      for (int r = 0; r < 16; ++r) acc[r] = __builtin_fmaf(wx6[r], xv, bh6[r]);

      #pragma unroll
      for (int kt = 0; kt < 8; ++kt) {
        const bf16x8 bhv = hbuf[rb][0][kt][lane];
        const bf16x8 blv = hbuf[rb][1][kt][lane];
        acc = mfma_bf16(Ahi[kt], bhv, acc);   // Whi * hhi
        acc = mfma_bf16(Alo[kt], bhv, acc);   // Wlo * hhi
        acc = mfma_bf16(Ahi[kt], blv, acc);   // Whi * hlo
      }

      // tanh + hi/lo split; write next h in B-fragment order.
      // acc reg r holds D[m][n] with local row (r&3)+8*(r>>2)+4*g; rows 0..15
      // of this wave's 32-row band go to ktile 2*wv (j = local row index
      // pattern), rows 16..31 to ktile 2*wv+1.
      unsigned hp[8], lp[8];
      #pragma unroll
      for (int r2 = 0; r2 < 8; ++r2) {
        const float t0 = fast_tanh(acc[2*r2]);
        const float t1 = fast_tanh(acc[2*r2+1]);
        split2(t0, t1, hp[r2], lp[r2]);
      }
      {
        u32x4 a = {hp[0],hp[1],hp[2],hp[3]}, b = {hp[4],hp[5],hp[6],hp[7]};
        u32x4 c = {lp[0],lp[1],lp[2],lp[3]}, d = {lp[4],lp[5],lp[6],lp[7]};
        hbuf[wb][0][2*wv  ][lane] = bitcast<bf16x8>(a);
        hbuf[wb][0][2*wv+1][lane] = bitcast<bf16x8>(b);
        hbuf[wb][1][2*wv  ][lane] = bitcast<bf16x8>(c);
        hbuf[wb][1][2*wv+1][lane] = bitcast<bf16x8>(d);
      }
      __syncthreads();
    }
    xc = xn;
  }

  // ---- final projection: out[b][c] = w_ph[c,:] . h_last[:,b] + b_p[c] ----
  // h_last sits in hbuf[0] (last step wrote buffer 0), hi+lo reconstruct.
  #pragma unroll
  for (int pass = 0; pass < 2; ++pass) {
    const int idx = tid + pass*256;
    const int c = idx >> 5;
    const int n = idx & 31;
    if (c < RNN_C) {
      float sum = b_p[c];
      for (int k = 0; k < RNN_H; ++k) {
        const int kt  = k >> 4, kk = k & 15;
        const int lp_ = n + 32*((kk>>2)&1);
        const int j   = (kk&3) + 4*(kk>>3);
        const unsigned short* ph = (const unsigned short*)&hbuf[0][0][kt][lp_];
        const unsigned short* pl = (const unsigned short*)&hbuf[0][1][kt][lp_];
        const float hv = __uint_as_float(((unsigned)ph[j]) << 16)
                       + __uint_as_float(((unsigned)pl[j]) << 16);
        sum = __builtin_fmaf(w_ph[c*RNN_H + k], hv, sum);
      }
      out[(size_t)(n0 + n)*RNN_C + c] = sum;
    }
  }
}

extern "C" void kernel_launch(void* const* d_in, const int* in_sizes, int n_in,
                              void* d_out, int out_size, void* d_ws, size_t ws_size,
                              hipStream_t stream) {
  (void)in_sizes; (void)n_in; (void)out_size; (void)d_ws; (void)ws_size;
  const float* x    = (const float*)d_in[0];
  const float* w_hx = (const float*)d_in[1];
  const float* w_hh = (const float*)d_in[2];
  const float* b_h  = (const float*)d_in[3];
  const float* w_ph = (const float*)d_in[4];
  const float* b_p  = (const float*)d_in[5];
  float* out = (float*)d_out;
  rnn_fused<<<dim3(RNN_B/32), dim3(256), 0, stream>>>(x, w_hx, w_hh, b_h, w_ph, b_p, out);
}

// Round 2
// 2138.289 us; speedup vs baseline: 1.0434x; 1.0434x over previous
//
#include <hip/hip_runtime.h>
#include <hip/hip_bf16.h>

typedef short    bf16x8 __attribute__((ext_vector_type(8)));
typedef float    f32x16 __attribute__((ext_vector_type(16)));
typedef float    f32x4  __attribute__((ext_vector_type(4)));
typedef unsigned u32x4  __attribute__((ext_vector_type(4)));

#define RNN_H 128
#define RNN_T 2048
#define RNN_B 8192
#define RNN_C 10

template <typename D, typename S>
__device__ __forceinline__ D bitcast(const S& s) {
  static_assert(sizeof(D) == sizeof(S), "size mismatch");
  D d; __builtin_memcpy(&d, &s, sizeof(D)); return d;
}

__device__ __forceinline__ unsigned pk_bf16(float a0, float a1) {
  __hip_bfloat162 b2 = __float22bfloat162_rn(make_float2(a0, a1));
  unsigned u; __builtin_memcpy(&u, &b2, 4);
  return u;  // a0 in low 16, a1 in high 16
}

// Dekker-style split: a ~= hi + lo with hi,lo bf16; residual ~2^-17 * |a|
__device__ __forceinline__ void split2(float a0, float a1, unsigned &hp, unsigned &lp) {
  hp = pk_bf16(a0, a1);
  float h0 = __uint_as_float(hp << 16);
  float h1 = __uint_as_float(hp & 0xffff0000u);
  lp = pk_bf16(a0 - h0, a1 - h1);
}

__device__ __forceinline__ float fast_tanh(float a) {
  // tanh(a) = 1 - 2/(exp(2a)+1);  exp(2a) = 2^(a * 2*log2(e))
  float e = __builtin_amdgcn_exp2f(a * 2.885390081777927f);
  return 1.0f - 2.0f * __builtin_amdgcn_rcpf(e + 1.0f);
}

__device__ __forceinline__ f32x16 mfma_bf16(bf16x8 a, bf16x8 b, f32x16 c) {
  return __builtin_amdgcn_mfma_f32_32x32x16_bf16(a, b, c, 0, 0, 0);
}

__global__ __launch_bounds__(256, 1)
void rnn_fused(const float* __restrict__ x, const float* __restrict__ w_hx,
               const float* __restrict__ w_hh, const float* __restrict__ b_h,
               const float* __restrict__ w_ph, const float* __restrict__ b_p,
               float* __restrict__ out)
{
  // h state double-buffered in LDS, stored directly in MFMA B-fragment order:
  // [buf][hi/lo][ktile(8)][lane(64)] -> 8 bf16 (16B) per slot. 32 KiB total.
  // Slot (kt, l, j) holds h[k][n] with n = l&31,
  //   k = kt*16 + 4*(l>>5) + (j&3) + 8*(j>>2).
  __shared__ bf16x8 hbuf[2][2][8][64];

  const int tid  = threadIdx.x;
  const int lane = tid & 63;
  const int wv   = tid >> 6;   // wave id: owns output rows 32*wv .. 32*wv+31
  const int g    = lane >> 5;
  const int l31  = lane & 31;
  const int n0   = blockIdx.x * 32;

  // zero initial h buffer (buf 0, hi+lo halves)
  {
    bf16x8 z = {0,0,0,0,0,0,0,0};
    bf16x8* p = &hbuf[0][0][0][0];
    for (int i = tid; i < 2*8*64; i += 256) p[i] = z;
  }

  // ---- W_hh A-fragments (hi/lo bf16 split), register-resident for all T ----
  bf16x8 Ahi[8], Alo[8];
  {
    const float* wrow = w_hh + (size_t)(wv*32 + l31)*RNN_H + 4*g;
    #pragma unroll
    for (int kt = 0; kt < 8; ++kt) {
      f32x4 w0 = *(const f32x4*)(wrow + kt*16);      // k offsets 0..3
      f32x4 w1 = *(const f32x4*)(wrow + kt*16 + 8);  // k offsets 8..11
      unsigned h0,h1,h2,h3,l0,l1,l2,l3;
      split2(w0[0], w0[1], h0, l0);
      split2(w0[2], w0[3], h1, l1);
      split2(w1[0], w1[1], h2, l2);
      split2(w1[2], w1[3], h3, l3);
      u32x4 th = {h0,h1,h2,h3}, tl = {l0,l1,l2,l3};
      Ahi[kt] = bitcast<bf16x8>(th);
      Alo[kt] = bitcast<bf16x8>(tl);
    }
  }

  // per-acc-register bias and w_hx (C/D row map: m = 32*wv + (r&3)+8*(r>>2)+4*g)
  f32x16 bh6, wx6;
  #pragma unroll
  for (int r = 0; r < 16; ++r) {
    const int m = wv*32 + (r&3) + 8*(r>>2) + 4*g;
    bh6[r] = b_h[m];
    wx6[r] = w_hx[m];
  }

  // x: this lane's batch row, prefetched 4 steps at a time
  const float* px = x + (size_t)(n0 + l31) * RNN_T;
  f32x4 xc = *(const f32x4*)px;

  __syncthreads();

  for (int t4 = 0; t4 < RNN_T/4; ++t4) {
    f32x4 xn = xc;
    if (t4 + 1 < RNN_T/4) xn = *(const f32x4*)(px + 4*t4 + 4);
    #pragma unroll
    for (int q = 0; q < 4; ++q) {
      const int rb = q & 1;      // read buffer (t even -> 0)
      const int wb = rb ^ 1;     // write buffer
      const float xv = xc[q];

      // three INDEPENDENT accumulator chains -> MFMA dep-latency hidden
      f32x16 c0, c1, c2;
      #pragma unroll
      for (int r = 0; r < 16; ++r) {
        c0[r] = __builtin_fmaf(wx6[r], xv, bh6[r]);
        c1[r] = 0.0f;
        c2[r] = 0.0f;
      }

      #pragma unroll
      for (int kt = 0; kt < 8; ++kt) {
        const bf16x8 bhv = hbuf[rb][0][kt][lane];
        const bf16x8 blv = hbuf[rb][1][kt][lane];
        c0 = mfma_bf16(Ahi[kt], bhv, c0);   // Whi * hhi
        c1 = mfma_bf16(Alo[kt], bhv, c1);   // Wlo * hhi
        c2 = mfma_bf16(Ahi[kt], blv, c2);   // Whi * hlo
      }

      // merge chains, tanh, hi/lo split; write next h in B-fragment order.
      unsigned hp[8], lp[8];
      #pragma unroll
      for (int r2 = 0; r2 < 8; ++r2) {
        const float a0 = (c0[2*r2]   + c1[2*r2])   + c2[2*r2];
        const float a1 = (c0[2*r2+1] + c1[2*r2+1]) + c2[2*r2+1];
        const float t0 = fast_tanh(a0);
        const float t1 = fast_tanh(a1);
        split2(t0, t1, hp[r2], lp[r2]);
      }
      {
        u32x4 a = {hp[0],hp[1],hp[2],hp[3]}, b = {hp[4],hp[5],hp[6],hp[7]};
        u32x4 c = {lp[0],lp[1],lp[2],lp[3]}, d = {lp[4],lp[5],lp[6],lp[7]};
        hbuf[wb][0][2*wv  ][lane] = bitcast<bf16x8>(a);
        hbuf[wb][0][2*wv+1][lane] = bitcast<bf16x8>(b);
        hbuf[wb][1][2*wv  ][lane] = bitcast<bf16x8>(c);
        hbuf[wb][1][2*wv+1][lane] = bitcast<bf16x8>(d);
      }
      // LDS-only barrier: order ds_write -> (cross-wave) ds_read without
      // draining vmcnt (keeps the x prefetch in flight).
      asm volatile("s_waitcnt lgkmcnt(0)\n\ts_barrier" ::: "memory");
    }
    xc = xn;
  }

  // ---- final projection: out[b][c] = w_ph[c,:] . h_last[:,b] + b_p[c] ----
  // h_last sits in hbuf[0] (last step wrote buffer 0), hi+lo reconstruct.
  #pragma unroll
  for (int pass = 0; pass < 2; ++pass) {
    const int idx = tid + pass*256;
    const int c = idx >> 5;
    const int n = idx & 31;
    if (c < RNN_C) {
      float sum = b_p[c];
      for (int k = 0; k < RNN_H; ++k) {
        const int kt  = k >> 4, kk = k & 15;
        const int lp_ = n + 32*((kk>>2)&1);
        const int j   = (kk&3) + 4*(kk>>3);
        const unsigned short* ph = (const unsigned short*)&hbuf[0][0][kt][lp_];
        const unsigned short* pl = (const unsigned short*)&hbuf[0][1][kt][lp_];
        const float hv = __uint_as_float(((unsigned)ph[j]) << 16)
                       + __uint_as_float(((unsigned)pl[j]) << 16);
        sum = __builtin_fmaf(w_ph[c*RNN_H + k], hv, sum);
      }
      out[(size_t)(n0 + n)*RNN_C + c] = sum;
    }
  }
}

extern "C" void kernel_launch(void* const* d_in, const int* in_sizes, int n_in,
                              void* d_out, int out_size, void* d_ws, size_t ws_size,
                              hipStream_t stream) {
  (void)in_sizes; (void)n_in; (void)out_size; (void)d_ws; (void)ws_size;
  const float* x    = (const float*)d_in[0];
  const float* w_hx = (const float*)d_in[1];
  const float* w_hh = (const float*)d_in[2];
  const float* b_h  = (const float*)d_in[3];
  const float* w_ph = (const float*)d_in[4];
  const float* b_p  = (const float*)d_in[5];
  float* out = (float*)d_out;
  rnn_fused<<<dim3(RNN_B/32), dim3(256), 0, stream>>>(x, w_hx, w_hh, b_h, w_ph, b_p, out);
}

// Round 3
// 1618.912 us; speedup vs baseline: 1.3782x; 1.3208x over previous
//
#include <hip/hip_runtime.h>
#include <hip/hip_bf16.h>

typedef short    bf16x8 __attribute__((ext_vector_type(8)));
typedef float    f32x4  __attribute__((ext_vector_type(4)));
typedef unsigned u32x4  __attribute__((ext_vector_type(4)));

#define RNN_H 128
#define RNN_T 2048
#define RNN_B 8192
#define RNN_C 10
#define BLK_N 16

template <typename D, typename S>
__device__ __forceinline__ D bitcast(const S& s) {
  static_assert(sizeof(D) == sizeof(S), "size mismatch");
  D d; __builtin_memcpy(&d, &s, sizeof(D)); return d;
}

__device__ __forceinline__ unsigned pk_bf16(float a0, float a1) {
  __hip_bfloat162 b2 = __float22bfloat162_rn(make_float2(a0, a1));
  unsigned u; __builtin_memcpy(&u, &b2, 4);
  return u;  // a0 in low 16, a1 in high 16
}

// setup-time RNE split for W: a ~= hi + lo, residual ~2^-17 |a|
__device__ __forceinline__ void split2(float a0, float a1, unsigned &hp, unsigned &lp) {
  hp = pk_bf16(a0, a1);
  float h0 = __uint_as_float(hp << 16);
  float h1 = __uint_as_float(hp & 0xffff0000u);
  lp = pk_bf16(a0 - h0, a1 - h1);
}

__device__ __forceinline__ float fast_tanh(float a) {
  // tanh(a) = 1 - 2/(exp(2a)+1)
  float e = __builtin_amdgcn_exp2f(a * 2.885390081777927f);
  return 1.0f - 2.0f * __builtin_amdgcn_rcpf(e + 1.0f);
}

__device__ __forceinline__ f32x4 mfma16(bf16x8 a, bf16x8 b, f32x4 c) {
  return __builtin_amdgcn_mfma_f32_16x16x32_bf16(a, b, c, 0, 0, 0);
}

// k-bijection for 16x16x32 frags (same map used for A-load and B-store, so the
// true HW layout cancels): slot (g = lane>>4, j) -> k = 4*g + (j&3) + 16*(j>>2).
// Chosen so each thread's 8 C/D values (row = 4*g + r + 16*mt) form exactly one
// lane-local bf16x8 B-slot -> single ds_write_b128 per hi/lo.

__global__ __launch_bounds__(256, 2)
void rnn_fused(const float* __restrict__ x, const float* __restrict__ w_hx,
               const float* __restrict__ w_hh, const float* __restrict__ b_h,
               const float* __restrict__ w_ph, const float* __restrict__ b_p,
               float* __restrict__ out)
{
  // h double-buffered in LDS in B-frag order: [buf][hi/lo][kt(4)][lane(64)],
  // slot (kt,l,j) holds h[kt*32 + 4*(l>>4) + (j&3) + 16*(j>>2)][l&15]. 16 KiB.
  __shared__ bf16x8 hbuf[2][2][4][64];

  const int tid  = threadIdx.x;
  const int lane = tid & 63;
  const int wv   = tid >> 6;   // wave owns rows 32*wv .. 32*wv+31
  const int g    = lane >> 4;
  const int l15  = lane & 15;
  const int n0   = blockIdx.x * BLK_N;

  { // zero initial h (buf 0)
    bf16x8 z = {0,0,0,0,0,0,0,0};
    bf16x8* p = &hbuf[0][0][0][0];
    for (int i = tid; i < 2*4*64; i += 256) p[i] = z;
  }

  // ---- W_hh hi/lo A-fragments, register-resident (64 VGPRs) ----
  bf16x8 Ahi[2][4], Alo[2][4];
  #pragma unroll
  for (int mt = 0; mt < 2; ++mt) {
    const float* wrow = w_hh + (size_t)(wv*32 + mt*16 + l15)*RNN_H + 4*g;
    #pragma unroll
    for (int kt = 0; kt < 4; ++kt) {
      f32x4 w0 = *(const f32x4*)(wrow + kt*32);        // j=0..3  (k off 0..3)
      f32x4 w1 = *(const f32x4*)(wrow + kt*32 + 16);   // j=4..7  (k off 16..19)
      unsigned h0,h1,h2,h3,l0,l1,l2,l3;
      split2(w0[0], w0[1], h0, l0);
      split2(w0[2], w0[3], h1, l1);
      split2(w1[0], w1[1], h2, l2);
      split2(w1[2], w1[3], h3, l3);
      u32x4 th = {h0,h1,h2,h3}, tl = {l0,l1,l2,l3};
      Ahi[mt][kt] = bitcast<bf16x8>(th);
      Alo[mt][kt] = bitcast<bf16x8>(tl);
    }
  }

  // bias / w_hx per C/D reg: m = wv*32 + mt*16 + 4*g + r
  f32x4 bh[2], wx[2];
  #pragma unroll
  for (int mt = 0; mt < 2; ++mt)
    #pragma unroll
    for (int r = 0; r < 4; ++r) {
      const int m = wv*32 + mt*16 + 4*g + r;
      bh[mt][r] = b_h[m];
      wx[mt][r] = w_hx[m];
    }

  // x for this lane's batch column, prefetched 4 steps at a time
  const float* px = x + (size_t)(n0 + l15) * RNN_T;
  f32x4 xc = *(const f32x4*)px;

  const f32x4 ZV = {0.0f, 0.0f, 0.0f, 0.0f};  // persistent zero C operand

  __syncthreads();

  for (int t4 = 0; t4 < RNN_T/4; ++t4) {
    f32x4 xn = xc;
    if (t4 + 1 < RNN_T/4) xn = *(const f32x4*)(px + 4*t4 + 4);
    #pragma unroll
    for (int q = 0; q < 4; ++q) {
      const int rb = q & 1;
      const int wb = rb ^ 1;
      const float xv = xc[q];

      f32x4 c0[2], c1[2], c2[2];
      #pragma unroll
      for (int mt = 0; mt < 2; ++mt)
        #pragma unroll
        for (int r = 0; r < 4; ++r)
          c0[mt][r] = __builtin_fmaf(wx[mt][r], xv, bh[mt][r]);

      // 6 independent MFMA chains of depth 4
      #pragma unroll
      for (int kt = 0; kt < 4; ++kt) {
        const bf16x8 bhv = hbuf[rb][0][kt][lane];
        const bf16x8 blv = hbuf[rb][1][kt][lane];
        c0[0] = mfma16(Ahi[0][kt], bhv, c0[0]);
        c0[1] = mfma16(Ahi[1][kt], bhv, c0[1]);
        c1[0] = mfma16(Alo[0][kt], bhv, kt ? c1[0] : ZV);
        c1[1] = mfma16(Alo[1][kt], bhv, kt ? c1[1] : ZV);
        c2[0] = mfma16(Ahi[0][kt], blv, kt ? c2[0] : ZV);
        c2[1] = mfma16(Ahi[1][kt], blv, kt ? c2[1] : ZV);
      }

      // merge + tanh + cheap trunc-hi / RNE-lo split; one b128 write per half.
      unsigned hw[4], lw[4];
      #pragma unroll
      for (int w = 0; w < 4; ++w) {
        const int mt = w >> 1, r0 = 2*(w & 1);
        const float v0 = (c0[mt][r0]   + c1[mt][r0])   + c2[mt][r0];
        const float v1 = (c0[mt][r0+1] + c1[mt][r0+1]) + c2[mt][r0+1];
        const float t0 = fast_tanh(v0);
        const float t1 = fast_tanh(v1);
        const unsigned u0 = __float_as_uint(t0), u1 = __float_as_uint(t1);
        const unsigned hp = (u1 & 0xffff0000u) | (u0 >> 16);  // trunc-bf16 pack
        hw[w] = hp;
        const float e0 = t0 - __uint_as_float(hp << 16);       // exact residual
        const float e1 = t1 - __uint_as_float(hp & 0xffff0000u);
        lw[w] = pk_bf16(e0, e1);
      }
      {
        u32x4 a = {hw[0],hw[1],hw[2],hw[3]}, b = {lw[0],lw[1],lw[2],lw[3]};
        hbuf[wb][0][wv][lane] = bitcast<bf16x8>(a);
        hbuf[wb][1][wv][lane] = bitcast<bf16x8>(b);
      }
      // LDS-only barrier (don't drain vmcnt: keep x prefetch in flight)
      asm volatile("s_waitcnt lgkmcnt(0)\n\ts_barrier" ::: "memory");
    }
    xc = xn;
  }

  __syncthreads();

  // ---- projection: out[b][c] = w_ph[c,:] . h_last[:,b] + b_p[c] ----
  // h_last is in buf 0 (t=2047 odd wrote buffer 0).
  {
    const int c = tid >> 4;
    const int n = tid & 15;
    if (c < RNN_C) {
      float sum = b_p[c];
      for (int k = 0; k < RNN_H; ++k) {
        const int kt = k >> 5;
        const int l  = 16*((k & 15) >> 2) + n;
        const int j  = (k & 3) + 4*((k >> 4) & 1);
        const unsigned short* ph = (const unsigned short*)&hbuf[0][0][kt][l];
        const unsigned short* pl = (const unsigned short*)&hbuf[0][1][kt][l];
        const float hv = __uint_as_float(((unsigned)ph[j]) << 16)
                       + __uint_as_float(((unsigned)pl[j]) << 16);
        sum = __builtin_fmaf(w_ph[c*RNN_H + k], hv, sum);
      }
      out[(size_t)(n0 + n)*RNN_C + c] = sum;
    }
  }
}

extern "C" void kernel_launch(void* const* d_in, const int* in_sizes, int n_in,
                              void* d_out, int out_size, void* d_ws, size_t ws_size,
                              hipStream_t stream) {
  (void)in_sizes; (void)n_in; (void)out_size; (void)d_ws; (void)ws_size;
  const float* x    = (const float*)d_in[0];
  const float* w_hx = (const float*)d_in[1];
  const float* w_hh = (const float*)d_in[2];
  const float* b_h  = (const float*)d_in[3];
  const float* w_ph = (const float*)d_in[4];
  const float* b_p  = (const float*)d_in[5];
  float* out = (float*)d_out;
  rnn_fused<<<dim3(RNN_B/BLK_N), dim3(256), 0, stream>>>(x, w_hx, w_hh, b_h, w_ph, b_p, out);
}